// Round 6
// baseline (29.266 us; speedup 1.0000x reference)
//
#include <hip/hip_runtime.h>

// AttnCutLoss: loss = -mean_b sum_j log(output[b,j]) * softmax_j(f1(labels[b,:j+1]) / tau)
// f1 at cutoff k (csum c, total t): 2c/(k+t), 0 if t==0.
//
// s_j = (2*log2e/tau) * c_j / (k_j + t) in [0, ~1.52] -> exp2 needs no max-subtract.
// ln(o) = ln2 * log2(o). One wave per row, no LDS, no __syncthreads.
//
// COALESCED: lane i owns float4 [c*256 + 4i, +4) for chunks c=0..7.
// ALL 16 row loads issued via inline-asm global_load_dwordx4 (compiler cannot sink
// asm-volatile outputs -> guaranteed 16-deep MLP). s_waitcnt vmcnt(8) gates label
// use; vmcnt(0) gates output use; sched_barrier(0) after each (guide rule #18).

constexpr int L   = 2048;
constexpr int TPB = 256;                 // 4 waves = 4 rows per block
constexpr float TAU   = 0.95f;
constexpr float LOG2E = 1.4426950408889634f;
constexpr float LN2   = 0.6931471805599453f;

typedef float f32x4 __attribute__((ext_vector_type(4)));

__global__ __launch_bounds__(TPB, 4) void attncut_row_kernel(
    const float* __restrict__ output,   // [B, L]
    const float* __restrict__ labels,   // [B, L]
    float* __restrict__ rowloss,        // [B]
    int B)
{
    const int wave = threadIdx.x >> 6;
    const int lane = threadIdx.x & 63;
    const int row  = blockIdx.x * 4 + wave;

    const f32x4* l0 = reinterpret_cast<const f32x4*>(labels + (size_t)row * L) + lane;
    const f32x4* o0 = reinterpret_cast<const f32x4*>(output + (size_t)row * L) + lane;
    const f32x4* l4 = l0 + 256;          // chunk 4 base (4*64 f32x4 = 4096 B)
    const f32x4* o4 = o0 + 256;

    // ---- issue ALL 16 loads; asm-volatile pins them up front ----
    f32x4 lb[8], ov[8];
    asm volatile("global_load_dwordx4 %0, %1, off"             : "=v"(lb[0]) : "v"(l0));
    asm volatile("global_load_dwordx4 %0, %1, off offset:1024" : "=v"(lb[1]) : "v"(l0));
    asm volatile("global_load_dwordx4 %0, %1, off offset:2048" : "=v"(lb[2]) : "v"(l0));
    asm volatile("global_load_dwordx4 %0, %1, off offset:3072" : "=v"(lb[3]) : "v"(l0));
    asm volatile("global_load_dwordx4 %0, %1, off"             : "=v"(lb[4]) : "v"(l4));
    asm volatile("global_load_dwordx4 %0, %1, off offset:1024" : "=v"(lb[5]) : "v"(l4));
    asm volatile("global_load_dwordx4 %0, %1, off offset:2048" : "=v"(lb[6]) : "v"(l4));
    asm volatile("global_load_dwordx4 %0, %1, off offset:3072" : "=v"(lb[7]) : "v"(l4));
    asm volatile("global_load_dwordx4 %0, %1, off"             : "=v"(ov[0]) : "v"(o0));
    asm volatile("global_load_dwordx4 %0, %1, off offset:1024" : "=v"(ov[1]) : "v"(o0));
    asm volatile("global_load_dwordx4 %0, %1, off offset:2048" : "=v"(ov[2]) : "v"(o0));
    asm volatile("global_load_dwordx4 %0, %1, off offset:3072" : "=v"(ov[3]) : "v"(o0));
    asm volatile("global_load_dwordx4 %0, %1, off"             : "=v"(ov[4]) : "v"(o4));
    asm volatile("global_load_dwordx4 %0, %1, off offset:1024" : "=v"(ov[5]) : "v"(o4));
    asm volatile("global_load_dwordx4 %0, %1, off offset:2048" : "=v"(ov[6]) : "v"(o4));
    asm volatile("global_load_dwordx4 %0, %1, off offset:3072" : "=v"(ov[7]) : "v"(o4));

    // ---- wait for the 8 label loads only (8 output loads still in flight) ----
    asm volatile("s_waitcnt vmcnt(8)");
    __builtin_amdgcn_sched_barrier(0);

    // ---- labels -> 4-bit nibble per chunk ----
    unsigned nibs = 0u;
#pragma unroll
    for (int c = 0; c < 8; ++c) {
        unsigned b = (unsigned)lb[c][0] | ((unsigned)lb[c][1] << 1)
                   | ((unsigned)lb[c][2] << 2) | ((unsigned)lb[c][3] << 3);
        nibs |= b << (4 * c);
    }

    // ---- pack per-chunk counts (0..4) into 4 words, 16-bit fields ----
    unsigned w[4];
#pragma unroll
    for (int q = 0; q < 4; ++q) {
        unsigned c0 = __popc((nibs >> (8 * q)) & 0xFu);
        unsigned c1 = __popc((nibs >> (8 * q + 4)) & 0xFu);
        w[q] = c0 | (c1 << 16);
    }

    // ---- 4 packed inclusive wave-scans (overlap output-load latency) ----
#pragma unroll
    for (int d = 1; d < 64; d <<= 1) {
#pragma unroll
        for (int q = 0; q < 4; ++q) {
            unsigned n = __shfl_up(w[q], d, 64);
            if (lane >= d) w[q] += n;
        }
    }

    // ---- chunk totals (lane 63) and per-lane exclusive prefixes ----
    float T[8], E[8];
#pragma unroll
    for (int q = 0; q < 4; ++q) {
        unsigned tw = __shfl(w[q], 63, 64);
        unsigned own0 = __popc((nibs >> (8 * q)) & 0xFu);
        unsigned own1 = __popc((nibs >> (8 * q + 4)) & 0xFu);
        T[2 * q]     = (float)(tw & 0xFFFFu);
        T[2 * q + 1] = (float)(tw >> 16);
        E[2 * q]     = (float)((w[q] & 0xFFFFu) - own0);
        E[2 * q + 1] = (float)((w[q] >> 16) - own1);
    }
    const float total = ((T[0] + T[1]) + (T[2] + T[3])) + ((T[4] + T[5]) + (T[6] + T[7]));

    const float K2 = (total > 0.f) ? (2.f * LOG2E / TAU) : 0.f;

    // ---- wait for output loads, then consume from registers ----
    asm volatile("s_waitcnt vmcnt(0)");
    __builtin_amdgcn_sched_barrier(0);

    float Z = 0.f, Wd = 0.f;
    float off = 0.f;
#pragma unroll
    for (int c = 0; c < 8; ++c) {
        float cf = off + E[c];
        const unsigned nib = (nibs >> (4 * c)) & 0xFu;
        const float kb = total + (float)(c * 256 + 4 * lane);

        cf += (float)(nib & 1u);
        float e0 = __builtin_amdgcn_exp2f((K2 * cf) * __builtin_amdgcn_rcpf(kb + 1.f));
        Z += e0;  Wd = fmaf(__builtin_amdgcn_logf(ov[c][0]), e0, Wd);

        cf += (float)((nib >> 1) & 1u);
        float e1 = __builtin_amdgcn_exp2f((K2 * cf) * __builtin_amdgcn_rcpf(kb + 2.f));
        Z += e1;  Wd = fmaf(__builtin_amdgcn_logf(ov[c][1]), e1, Wd);

        cf += (float)((nib >> 2) & 1u);
        float e2 = __builtin_amdgcn_exp2f((K2 * cf) * __builtin_amdgcn_rcpf(kb + 3.f));
        Z += e2;  Wd = fmaf(__builtin_amdgcn_logf(ov[c][2]), e2, Wd);

        cf += (float)((nib >> 3) & 1u);
        float e3 = __builtin_amdgcn_exp2f((K2 * cf) * __builtin_amdgcn_rcpf(kb + 4.f));
        Z += e3;  Wd = fmaf(__builtin_amdgcn_logf(ov[c][3]), e3, Wd);

        off += T[c];
    }

    // ---- wave reduce Z, Wd ----
#pragma unroll
    for (int d = 32; d; d >>= 1) {
        Z  += __shfl_xor(Z, d, 64);
        Wd += __shfl_xor(Wd, d, 64);
    }
    if (lane == 0) rowloss[row] = -LN2 * Wd / Z;
}

__global__ __launch_bounds__(1024) void attncut_reduce_kernel(
    const float* __restrict__ rowloss, float* __restrict__ out, int B)
{
    const int t = threadIdx.x;
    const float4* r4 = reinterpret_cast<const float4*>(rowloss);
    float s = 0.f;
    for (int i = t; i < B / 4; i += 1024) {
        float4 v = r4[i];
        s += (v.x + v.y) + (v.z + v.w);
    }
#pragma unroll
    for (int d = 32; d; d >>= 1) s += __shfl_xor(s, d, 64);
    __shared__ float ws[16];
    if ((t & 63) == 0) ws[t >> 6] = s;
    __syncthreads();
    if (t < 16) {
        s = ws[t];
#pragma unroll
        for (int d = 8; d; d >>= 1) s += __shfl_xor(s, d, 64);
        if (t == 0) out[0] = s / (float)B;
    }
}

extern "C" void kernel_launch(void* const* d_in, const int* in_sizes, int n_in,
                              void* d_out, int out_size, void* d_ws, size_t ws_size,
                              hipStream_t stream) {
    const float* output = (const float*)d_in[0];   // [B, L, 1] fp32
    const float* labels = (const float*)d_in[1];   // [B, L]    fp32
    const int B = in_sizes[1] / L;                 // 8192

    float* rowloss = (float*)d_ws;                 // B floats = 32 KB scratch

    attncut_row_kernel<<<B / 4, TPB, 0, stream>>>(output, labels, rowloss, B);
    attncut_reduce_kernel<<<1, 1024, 0, stream>>>(rowloss, (float*)d_out, B);
}